// Round 1
// baseline (408.443 us; speedup 1.0000x reference)
//
#include <hip/hip_runtime.h>
#include <cstdint>
#include <cstddef>

typedef __bf16 bf16;
typedef __bf16 bf16x4 __attribute__((ext_vector_type(4)));
typedef __bf16 bf16x8 __attribute__((ext_vector_type(8)));
typedef float  f32x4  __attribute__((ext_vector_type(4)));
typedef short  s16x4  __attribute__((ext_vector_type(4)));

#define HIDDEN 2048
#define NHEADS 16
#define HDIM   128
#define BSZ    2
#define SEQ    2048
#define BS     (BSZ*SEQ)     /* 4096 rows */
#define QKW    (2*HIDDEN)    /* 4096: Q|K concat width */

union b4u { bf16x4 h; s16x4 s; };

// async global->LDS, 16B per lane. LDS dest = wave-uniform base + lane*16.
__device__ __forceinline__ void async16(const bf16* g, bf16* l) {
    __builtin_amdgcn_global_load_lds(
        (const __attribute__((address_space(1))) unsigned int*)g,
        (__attribute__((address_space(3))) unsigned int*)l, 16, 0, 0);
}

#define BARX()  asm volatile("s_barrier" ::: "memory")
#define VMW(N)  asm volatile("s_waitcnt vmcnt(" #N ")" ::: "memory")

// ---------------------------------------------------------------- fused casts + rope table
__global__ __launch_bounds__(256) void cast_all(const float* __restrict__ hs,
                                                const float* __restrict__ Wq,
                                                const float* __restrict__ Wk,
                                                const float* __restrict__ Wv,
                                                const float* __restrict__ Wo,
                                                const int* __restrict__ pos,
                                                bf16* __restrict__ hs_b,
                                                bf16* __restrict__ wqkv,
                                                bf16* __restrict__ wo_b,
                                                float2* __restrict__ tab) {
    int i = blockIdx.x * 256 + threadIdx.x;
    if (i >= 6291456) {                       // rope table region
        int j = i - 6291456;                  // 0..131071
        int s = j >> 6, p = j & 63;
        float t = (float)pos[s];
        float inv = expf(-(float)(2 * p) * (9.2103403719761836f / 128.0f));
        float sn, cs;
        sincosf(t * inv, &sn, &cs);
        tab[j] = make_float2(cs, sn);
        return;
    }
    const float* src; bf16* dst; int off;
    if (i < 2097152) { src = hs; dst = hs_b; off = i; }
    else {
        int j = i - 2097152;
        int r = j >> 20;
        off = j & 1048575;
        if      (r == 0) { src = Wq; dst = wqkv; }
        else if (r == 1) { src = Wk; dst = wqkv + (size_t)4194304; }
        else if (r == 2) { src = Wv; dst = wqkv + (size_t)8388608; }
        else             { src = Wo; dst = wo_b; }
    }
    const float4 v = ((const float4*)src)[off];
    bf16x4 o;
    o.x = (bf16)v.x; o.y = (bf16)v.y; o.z = (bf16)v.z; o.w = (bf16)v.w;
    ((bf16x4*)dst)[off] = o;
}

// ---------------------------------------------------------------- fused QKV GEMM + RoPE + V^T
// 256x256 tile, BK=32, 512 thr (8 waves, 2M x 4N), ring-4 LDS (4 x 32KB K-tiles),
// counted-vmcnt deep pipeline (3 K-tiles in flight), st_16x32 XOR swizzle,
// setprio(1) around MFMA clusters. Grid 24x16 = 384 blocks, XCD-swizzled.
//
// Q/K-region B rows are PERMUTED into LDS so that head-dim d and d+64 share a lane:
// LDS n-slot n holds W-row perm(n); perm swaps bits so frag nf pairs with nf+2 (+64 cols).
__device__ __forceinline__ int qk_perm(int n) {
    int wl = n >> 6, j = n & 63;
    return ((wl >> 1) << 7) | ((j >> 5) << 6) | ((wl & 1) << 5) | (j & 31);
}

// One K-tile: 2 phases x {ds_read frags | stage 2 loads | barrier | 16 MFMA | barrier}.
// vmcnt once per K-tile (phase B), counted so tiles t+2,t+3 stay in flight.
#define QKV_TILE(T, DOSTAGE, VMN) do {                                          \
    const int bufR_ = (T) & 3;                                                  \
    const bf16* lAr = smem + bufR_ * 16384 + (wm * 128 + l15) * 32 + colE;      \
    const bf16* lBr = smem + bufR_ * 16384 + 8192 + (wn * 64 + l15) * 32 + colE;\
    bf16x8 bfr[4], af[4];                                                       \
    _Pragma("unroll") for (int nf = 0; nf < 4; ++nf)                            \
        bfr[nf] = *(const bf16x8*)(lBr + nf * 512);                             \
    _Pragma("unroll") for (int mf = 0; mf < 4; ++mf)                            \
        af[mf] = *(const bf16x8*)(lAr + mf * 512);                              \
    if (DOSTAGE) {                                                              \
        bf16* dA = smem + (((T) + 3) & 3) * 16384 + w * 512;                    \
        async16(pa0 + ((T) + 3) * 32, dA);                                      \
        async16(pa1 + ((T) + 3) * 32, dA + 4096);                               \
    }                                                                           \
    BARX();                                                                     \
    __builtin_amdgcn_s_setprio(1);                                              \
    _Pragma("unroll") for (int mf = 0; mf < 4; ++mf)                            \
    _Pragma("unroll") for (int nf = 0; nf < 4; ++nf)                            \
        acc[mf][nf] = __builtin_amdgcn_mfma_f32_16x16x32_bf16(                  \
            af[mf], bfr[nf], acc[mf][nf], 0, 0, 0);                             \
    __builtin_amdgcn_s_setprio(0);                                              \
    BARX();                                                                     \
    _Pragma("unroll") for (int mf = 0; mf < 4; ++mf)                            \
        af[mf] = *(const bf16x8*)(lAr + 2048 + mf * 512);                       \
    if (DOSTAGE) {                                                              \
        bf16* dB = smem + (((T) + 3) & 3) * 16384 + 8192 + w * 512;             \
        async16(pb0 + ((T) + 3) * 32, dB);                                      \
        async16(pb1 + ((T) + 3) * 32, dB + 4096);                               \
    }                                                                           \
    VMW(VMN);                                                                   \
    BARX();                                                                     \
    __builtin_amdgcn_s_setprio(1);                                              \
    _Pragma("unroll") for (int mf = 0; mf < 4; ++mf)                            \
    _Pragma("unroll") for (int nf = 0; nf < 4; ++nf)                            \
        acc[4 + mf][nf] = __builtin_amdgcn_mfma_f32_16x16x32_bf16(              \
            af[mf], bfr[nf], acc[4 + mf][nf], 0, 0, 0);                         \
    __builtin_amdgcn_s_setprio(0);                                              \
    BARX();                                                                     \
} while (0)

__global__ __launch_bounds__(512, 2) void gemm_qkv(const bf16* __restrict__ A,
                                                   const bf16* __restrict__ Bt,
                                                   const float2* __restrict__ tab,
                                                   bf16* __restrict__ qk,
                                                   bf16* __restrict__ vtb) {
    // ring-4: buf b at [b*16384, +16384) elems; A k-tile first 8192, B next 8192.
    __shared__ alignas(16) bf16 smem[65536];   // 128 KiB

    const int tid  = threadIdx.x;
    const int lane = tid & 63;
    const int w    = tid >> 6;
    const int l15  = lane & 15;
    const int quad = lane >> 4;
    const int wm   = w >> 2;       // 0..1
    const int wn   = w & 3;        // 0..3

    // XCD-aware bijective block swizzle (384 % 8 == 0)
    int raw = blockIdx.y * 24 + blockIdx.x;
    int wg  = (raw & 7) * 48 + (raw >> 3);
    const int mTile = (wg / 24) * 256;
    const int nTile = (wg % 24) * 256;

    // ---- per-thread staging source (pre-inverse-swizzled global addresses) ----
    // linear LDS slot: row = w*16 + lane/4 (+ s*128), colElem = (lane&3)*8;
    // st_16x32 swizzle: rows with bit3 set swap 16-elem halves -> XOR source col.
    const int sRow  = w * 16 + (lane >> 2);                       // 0..127
    const int sColE = ((lane & 3) * 8) ^ ((lane & 32) ? 16 : 0);  // elems in [0,32)
    const bf16* pa0 = A + (size_t)(mTile + sRow) * HIDDEN + sColE;
    const bf16* pa1 = pa0 + (size_t)128 * HIDDEN;
    int n0 = sRow, n1 = sRow + 128;
    if (nTile < QKW) { n0 = qk_perm(n0); n1 = qk_perm(n1); }
    const bf16* pb0 = Bt + (size_t)(nTile + n0) * HIDDEN + sColE;
    const bf16* pb1 = Bt + (size_t)(nTile + n1) * HIDDEN + sColE;

    // ---- read-side swizzled column (row&8 constant = l15&8 across all frags) ----
    const int colE = (quad * 8) ^ ((l15 & 8) ? 16 : 0);

    f32x4 acc[8][4];
#pragma unroll
    for (int i = 0; i < 8; ++i)
#pragma unroll
        for (int j = 0; j < 4; ++j) acc[i][j] = (f32x4){0.f, 0.f, 0.f, 0.f};

    // ---- prologue: stage K-tiles 0,1,2; wait tile0 landed (8 = tiles 1,2 in flight)
#pragma unroll
    for (int tt = 0; tt < 3; ++tt) {
        bf16* dA = smem + tt * 16384 + w * 512;
        async16(pa0 + tt * 32, dA);
        async16(pa1 + tt * 32, dA + 4096);
        async16(pb0 + tt * 32, dA + 8192);
        async16(pb1 + tt * 32, dA + 8192 + 4096);
    }
    VMW(8);
    BARX();

    // ---- main loop: 64 K-tiles; stage tile t+3 during tile t ----
#pragma unroll 4
    for (int t = 0; t < 60; ++t) QKV_TILE(t, 1, 8);
    QKV_TILE(60, 1, 8);
    QKV_TILE(61, 0, 4);
    QKV_TILE(62, 0, 0);
    QKV_TILE(63, 0, 0);

    // ---- epilogue ----
    if (nTile < QKW) {
        // RoPE: frag nf holds cols d=(wn&1)*32+(nf&1)*16+l15 (+64 for nf+2), same lane.
        const int hbase = nTile + (wn >> 1) * 128 + (wn & 1) * 32;
#pragma unroll
        for (int mf = 0; mf < 8; ++mf)
#pragma unroll
            for (int r = 0; r < 4; ++r) {
                int row = mTile + wm * 128 + mf * 16 + quad * 4 + r;
                int s   = row & (SEQ - 1);
                float2 t0 = tab[s * 64 + (wn & 1) * 32 + l15];
                float2 t1 = tab[s * 64 + (wn & 1) * 32 + 16 + l15];
                size_t rb = (size_t)row * QKW + hbase + l15;
                float lo0 = acc[mf][0][r], hi0 = acc[mf][2][r];
                float lo1 = acc[mf][1][r], hi1 = acc[mf][3][r];
                qk[rb]      = (bf16)(lo0 * t0.x - hi0 * t0.y);
                qk[rb + 64] = (bf16)(hi0 * t0.x + lo0 * t0.y);
                qk[rb + 16] = (bf16)(lo1 * t1.x - hi1 * t1.y);
                qk[rb + 80] = (bf16)(hi1 * t1.x + lo1 * t1.y);
            }
    } else {
        // V region (identity n-map): store transposed, vt[feature][token]
#pragma unroll
        for (int mf = 0; mf < 8; ++mf)
#pragma unroll
            for (int nf = 0; nf < 4; ++nf) {
                int col_v = (nTile - QKW) + wn * 64 + nf * 16 + l15;
                int row0  = mTile + wm * 128 + mf * 16 + quad * 4;
                bf16x4 pk;
#pragma unroll
                for (int r = 0; r < 4; ++r) pk[r] = (bf16)acc[mf][nf][r];
                *(bf16x4*)(vtb + (size_t)col_v * BS + row0) = pk;
            }
    }
}

// ---------------------------------------------------------------- GEMM: C = A * Bt^T (final proj)
template <typename OutT>
__global__ __launch_bounds__(256) void gemm_bt(const bf16* __restrict__ A,
                                               const bf16* __restrict__ Bt,
                                               OutT* __restrict__ C,
                                               int M, int N, int K) {
    __shared__ bf16 Als[128 * 32];
    __shared__ bf16 Bls[128 * 32];
    const int tid  = threadIdx.x;
    const int lane = tid & 63;
    const int w    = tid >> 6;
    const int l15  = lane & 15;
    const int quad = lane >> 4;
    const int mTile = blockIdx.y * 128;
    const int nTile = blockIdx.x * 128;
    const int wm = (w >> 1) * 64;
    const int wn = (w & 1) * 64;

    f32x4 acc[4][4];
#pragma unroll
    for (int i = 0; i < 4; ++i)
#pragma unroll
        for (int j = 0; j < 4; ++j) acc[i][j] = (f32x4){0.f, 0.f, 0.f, 0.f};

    const bf16* gA = A + (size_t)(mTile + w * 32 + (lane >> 2)) * K + (lane & 3) * 8;
    const bf16* gB = Bt + (size_t)(nTile + w * 32 + (lane >> 2)) * K + (lane & 3) * 8;
    bf16* lA = Als + w * 1024;
    bf16* lB = Bls + w * 1024;

    for (int k0 = 0; k0 < K; k0 += 32) {
        async16(gA + k0,          lA);
        async16(gA + 16 * K + k0, lA + 512);
        async16(gB + k0,          lB);
        async16(gB + 16 * K + k0, lB + 512);
        __syncthreads();

        bf16x8 af[4], bfr[4];
#pragma unroll
        for (int mi = 0; mi < 4; ++mi)
            af[mi] = *(const bf16x8*)(Als + (wm + mi * 16 + l15) * 32 + quad * 8);
#pragma unroll
        for (int ni = 0; ni < 4; ++ni)
            bfr[ni] = *(const bf16x8*)(Bls + (wn + ni * 16 + l15) * 32 + quad * 8);
#pragma unroll
        for (int mi = 0; mi < 4; ++mi)
#pragma unroll
            for (int ni = 0; ni < 4; ++ni)
                acc[mi][ni] = __builtin_amdgcn_mfma_f32_16x16x32_bf16(
                    af[mi], bfr[ni], acc[mi][ni], 0, 0, 0);
        __syncthreads();
    }

#pragma unroll
    for (int mi = 0; mi < 4; ++mi)
#pragma unroll
        for (int ni = 0; ni < 4; ++ni)
#pragma unroll
            for (int r = 0; r < 4; ++r) {
                int row = mTile + wm + mi * 16 + quad * 4 + r;
                int col = nTile + wn + ni * 16 + l15;
                C[(size_t)row * N + col] = (OutT)acc[mi][ni][r];
            }
}

// ---------------------------------------------------------------- flash attention (S^T form)
__global__ __launch_bounds__(256) void attn_kernel(const bf16* __restrict__ qk,
                                                   const bf16* __restrict__ vt,
                                                   bf16* __restrict__ ao) {
    __shared__ bf16 Kls[64 * 128];   // [j][d], 16B chunk c of row j at c^(j&7)
    __shared__ bf16 Vls[128 * 64];   // [d][s], swizzled same

    const int tid  = threadIdx.x;
    const int lane = tid & 63;
    const int w    = tid >> 6;
    const int l15  = lane & 15;
    const int quad = lane >> 4;
    const int bid  = blockIdx.x;
    const int qt   = 31 - (bid >> 5);   // longest blocks dispatch first
    const int bh   = bid & 31;
    const int b    = bh >> 4;
    const int h    = bh & 15;
    const int qbase = qt * 64;
    const size_t seq0 = (size_t)b * SEQ;

    bf16x8 qf[4];
    {
        const bf16* qp = qk + (seq0 + qbase + w * 16 + l15) * QKW + h * HDIM + quad * 8;
#pragma unroll
        for (int ks = 0; ks < 4; ++ks) qf[ks] = *(const bf16x8*)(qp + ks * 32);
    }

    f32x4 o[8];
#pragma unroll
    for (int i = 0; i < 8; ++i) o[i] = (f32x4){0.f, 0.f, 0.f, 0.f};
    float m_s = -3e38f, l_s = 0.f;
    const int qg = qbase + w * 16 + l15;

    const int krow = lane >> 4;
    const int kp   = lane & 15;
    const int vrow = lane >> 3;
    const int vp   = lane & 7;
    const int sw   = l15 & 7;

    for (int t = 0; t <= qt; ++t) {
        const int kb = t * 64;
#pragma unroll
        for (int i = 0; i < 4; ++i) {
            int j = w * 16 + i * 4 + krow;
            int c = (kp & 8) | ((kp & 7) ^ (j & 7));
            async16(qk + (seq0 + kb + j) * QKW + HIDDEN + h * HDIM + c * 8,
                    Kls + (w * 4 + i) * 512);
        }
#pragma unroll
        for (int i = 0; i < 4; ++i) {
            int d = w * 32 + i * 8 + vrow;
            int c = vp ^ (d & 7);
            async16(vt + (size_t)(h * HDIM + d) * (size_t)BS + seq0 + kb + c * 8,
                    Vls + (w * 4 + i) * 512);
        }
        __syncthreads();

        f32x4 sa[4];
#pragma unroll
        for (int ni = 0; ni < 4; ++ni) sa[ni] = (f32x4){0.f, 0.f, 0.f, 0.f};
#pragma unroll
        for (int ni = 0; ni < 4; ++ni)
#pragma unroll
            for (int ks = 0; ks < 4; ++ks) {
                bf16x8 kf = *(const bf16x8*)(Kls + (ni * 16 + l15) * 128 +
                                             (((ks * 4 + quad) ^ sw) << 3));
                sa[ni] = __builtin_amdgcn_mfma_f32_16x16x32_bf16(kf, qf[ks], sa[ni], 0, 0, 0);
            }

        const float scale = 0.08838834764831845f * 1.4426950408889634f;
        float rmax = -3e38f;
        const bool diag = (t == qt);
#pragma unroll
        for (int ni = 0; ni < 4; ++ni)
#pragma unroll
            for (int r = 0; r < 4; ++r) {
                float sv = sa[ni][r] * scale;
                if (diag) {
                    int jg = kb + ni * 16 + quad * 4 + r;
                    if (jg > qg) sv = -1e30f;
                }
                sa[ni][r] = sv;
                rmax = fmaxf(rmax, sv);
            }
        rmax = fmaxf(rmax, __shfl_xor(rmax, 16));
        rmax = fmaxf(rmax, __shfl_xor(rmax, 32));

        float mn = fmaxf(m_s, rmax);
        float alpha = exp2f(m_s - mn);
        m_s = mn;
        float rsum = 0.f;
        b4u pb[4];
#pragma unroll
        for (int ni = 0; ni < 4; ++ni)
#pragma unroll
            for (int r = 0; r < 4; ++r) {
                float e = exp2f(sa[ni][r] - mn);
                rsum += e;
                pb[ni].h[r] = (bf16)e;
            }
        rsum += __shfl_xor(rsum, 16);
        rsum += __shfl_xor(rsum, 32);
        l_s = l_s * alpha + rsum;

        if (__ballot(alpha != 1.f) != 0ull) {
#pragma unroll
            for (int n2 = 0; n2 < 8; ++n2)
#pragma unroll
                for (int r = 0; r < 4; ++r) o[n2][r] *= alpha;
        }

#pragma unroll
        for (int n2 = 0; n2 < 8; ++n2)
#pragma unroll
            for (int ni = 0; ni < 4; ++ni) {
                b4u vf;
                vf.h = *(const bf16x4*)(Vls + (n2 * 16 + l15) * 64 +
                                        ((((ni * 2 + (quad >> 1)) ^ sw) << 3) + (quad & 1) * 4));
                o[n2] = __builtin_amdgcn_mfma_f32_16x16x16bf16_1k(vf.s, pb[ni].s, o[n2], 0, 0, 0);
            }
        __syncthreads();
    }

    const float inv = 1.0f / l_s;
    bf16* op = ao + (seq0 + qg) * HIDDEN + h * HDIM + quad * 4;
#pragma unroll
    for (int n2 = 0; n2 < 8; ++n2) {
        bf16x4 pk;
#pragma unroll
        for (int r = 0; r < 4; ++r) pk[r] = (bf16)(o[n2][r] * inv);
        *(bf16x4*)(op + n2 * 16) = pk;
    }
}

// ---------------------------------------------------------------- launch
extern "C" void kernel_launch(void* const* d_in, const int* in_sizes, int n_in,
                              void* d_out, int out_size, void* d_ws, size_t ws_size,
                              hipStream_t stream) {
    const float* hs = (const float*)d_in[0];
    const float* Wq = (const float*)d_in[1];
    const float* Wk = (const float*)d_in[2];
    const float* Wv = (const float*)d_in[3];
    const float* Wo = (const float*)d_in[4];
    const int* pos  = (const int*)d_in[6];
    float* out = (float*)d_out;

    bf16* hs_b = (bf16*)d_ws;                               //  8,388,608 el
    bf16* wqkv = hs_b + (size_t)8388608;                    // 12,582,912 el [6144][2048]
    bf16* wo_b = wqkv + (size_t)12582912;                   //  4,194,304 el
    bf16* qkb  = wo_b + (size_t)4194304;                    // 16,777,216 el [4096][4096]
    bf16* vtb  = qkb + (size_t)16777216;                    //  8,388,608 el [2048][4096]
    bf16* ao   = vtb + (size_t)8388608;                     //  8,388,608 el
    float2* tab = (float2*)ao;  // 1 MB, consumed by gemm_qkv BEFORE attn writes ao

    cast_all<<<25088, 256, 0, stream>>>(hs, Wq, Wk, Wv, Wo, pos, hs_b, wqkv, wo_b, tab);
    gemm_qkv<<<dim3(24, 16), 512, 0, stream>>>(hs_b, wqkv, tab, qkb, vtb);
    attn_kernel<<<1024, 256, 0, stream>>>(qkb, vtb, ao);
    gemm_bt<float><<<dim3(HIDDEN / 128, BS / 128), 256, 0, stream>>>(ao, wo_b, out, BS, HIDDEN, HIDDEN);
}

// Round 2
// 371.695 us; speedup vs baseline: 1.0989x; 1.0989x over previous
//
#include <hip/hip_runtime.h>
#include <cstdint>
#include <cstddef>

typedef __bf16 bf16;
typedef __bf16 bf16x4 __attribute__((ext_vector_type(4)));
typedef __bf16 bf16x8 __attribute__((ext_vector_type(8)));
typedef float  f32x4  __attribute__((ext_vector_type(4)));
typedef short  s16x4  __attribute__((ext_vector_type(4)));

#define HIDDEN 2048
#define NHEADS 16
#define HDIM   128
#define BSZ    2
#define SEQ    2048
#define BS     (BSZ*SEQ)     /* 4096 rows */
#define QKW    (2*HIDDEN)    /* 4096: Q|K concat width */

union b4u { bf16x4 h; s16x4 s; };

// async global->LDS, 16B per lane. LDS dest = wave-uniform base + lane*16.
__device__ __forceinline__ void async16(const bf16* g, bf16* l) {
    __builtin_amdgcn_global_load_lds(
        (const __attribute__((address_space(1))) unsigned int*)g,
        (__attribute__((address_space(3))) unsigned int*)l, 16, 0, 0);
}

#define BARX()  asm volatile("s_barrier" ::: "memory")
#define VMW(N)  asm volatile("s_waitcnt vmcnt(" #N ")" ::: "memory")

// ---------------------------------------------------------------- fused casts + rope table
__global__ __launch_bounds__(256) void cast_all(const float* __restrict__ hs,
                                                const float* __restrict__ Wq,
                                                const float* __restrict__ Wk,
                                                const float* __restrict__ Wv,
                                                const float* __restrict__ Wo,
                                                const int* __restrict__ pos,
                                                bf16* __restrict__ hs_b,
                                                bf16* __restrict__ wqkv,
                                                bf16* __restrict__ wo_b,
                                                float2* __restrict__ tab) {
    int i = blockIdx.x * 256 + threadIdx.x;
    if (i >= 6291456) {                       // rope table region
        int j = i - 6291456;                  // 0..131071
        int s = j >> 6, p = j & 63;
        float t = (float)pos[s];
        float inv = expf(-(float)(2 * p) * (9.2103403719761836f / 128.0f));
        float sn, cs;
        sincosf(t * inv, &sn, &cs);
        tab[j] = make_float2(cs, sn);
        return;
    }
    const float* src; bf16* dst; int off;
    if (i < 2097152) { src = hs; dst = hs_b; off = i; }
    else {
        int j = i - 2097152;
        int r = j >> 20;
        off = j & 1048575;
        if      (r == 0) { src = Wq; dst = wqkv; }
        else if (r == 1) { src = Wk; dst = wqkv + (size_t)4194304; }
        else if (r == 2) { src = Wv; dst = wqkv + (size_t)8388608; }
        else             { src = Wo; dst = wo_b; }
    }
    const float4 v = ((const float4*)src)[off];
    bf16x4 o;
    o.x = (bf16)v.x; o.y = (bf16)v.y; o.z = (bf16)v.z; o.w = (bf16)v.w;
    ((bf16x4*)dst)[off] = o;
}

// ---------------------------------------------------------------- fused QKV GEMM + RoPE + V^T
// 256x256 tile, BK=32, 512 thr (8 waves, 2M x 4N), ring-4 LDS (4 x 32KB K-tiles).
// Barrier-minimal: ONE {vmcnt(N); s_barrier} per K-tile. Stage targets buf t+3 (never the
// buf being read); the only inter-wave hazard is the tile boundary. Counted vmcnt keeps
// 2 K-tiles of loads in flight across the barrier. st_16x32 swizzle (linear LDS dest,
// inverse-swizzled global source, swizzled ds_read). setprio(1) around MFMA clusters.
__device__ __forceinline__ int qk_perm(int n) {
    int wl = n >> 6, j = n & 63;
    return ((wl >> 1) << 7) | ((j >> 5) << 6) | ((wl & 1) << 5) | (j & 31);
}

#define QKV_TILE(T, DOSTAGE, VMN) do {                                          \
    VMW(VMN);                                                                   \
    BARX();                                                                     \
    const bf16* lAr = lA0 + ((T) & 3) * 16384;                                  \
    const bf16* lBr = lB0 + ((T) & 3) * 16384;                                  \
    bf16x8 bfr[4], af[4];                                                       \
    _Pragma("unroll") for (int nf = 0; nf < 4; ++nf)                            \
        bfr[nf] = *(const bf16x8*)(lBr + nf * 512);                             \
    _Pragma("unroll") for (int mf = 0; mf < 4; ++mf)                            \
        af[mf] = *(const bf16x8*)(lAr + mf * 512);                              \
    if (DOSTAGE) {                                                              \
        bf16* dA = smem + (((T) + 3) & 3) * 16384 + w * 512;                    \
        async16(pa0 + ((T) + 3) * 32, dA);                                      \
        async16(pa1 + ((T) + 3) * 32, dA + 4096);                               \
    }                                                                           \
    __builtin_amdgcn_s_setprio(1);                                              \
    _Pragma("unroll") for (int mf = 0; mf < 4; ++mf)                            \
    _Pragma("unroll") for (int nf = 0; nf < 4; ++nf)                            \
        acc[mf][nf] = __builtin_amdgcn_mfma_f32_16x16x32_bf16(                  \
            af[mf], bfr[nf], acc[mf][nf], 0, 0, 0);                             \
    __builtin_amdgcn_s_setprio(0);                                              \
    _Pragma("unroll") for (int mf = 0; mf < 4; ++mf)                            \
        af[mf] = *(const bf16x8*)(lAr + 2048 + mf * 512);                       \
    if (DOSTAGE) {                                                              \
        bf16* dB = smem + (((T) + 3) & 3) * 16384 + 8192 + w * 512;             \
        async16(pb0 + ((T) + 3) * 32, dB);                                      \
        async16(pb1 + ((T) + 3) * 32, dB + 4096);                               \
    }                                                                           \
    __builtin_amdgcn_s_setprio(1);                                              \
    _Pragma("unroll") for (int mf = 0; mf < 4; ++mf)                            \
    _Pragma("unroll") for (int nf = 0; nf < 4; ++nf)                            \
        acc[4 + mf][nf] = __builtin_amdgcn_mfma_f32_16x16x32_bf16(              \
            af[mf], bfr[nf], acc[4 + mf][nf], 0, 0, 0);                         \
    __builtin_amdgcn_s_setprio(0);                                              \
} while (0)

__global__ __launch_bounds__(512, 2) void gemm_qkv(const bf16* __restrict__ A,
                                                   const bf16* __restrict__ Bt,
                                                   const float2* __restrict__ tab,
                                                   bf16* __restrict__ qk,
                                                   bf16* __restrict__ vtb) {
    __shared__ alignas(16) bf16 smem[65536];   // 128 KiB: 4 bufs x (A 8192 | B 8192)

    const int tid  = threadIdx.x;
    const int lane = tid & 63;
    const int w    = tid >> 6;
    const int l15  = lane & 15;
    const int quad = lane >> 4;
    const int wm   = w >> 2;       // 0..1
    const int wn   = w & 3;        // 0..3

    // n-band XCD mapping: XCD x = raw&7 owns nTiles [3x,3x+3), m-major sweep.
    // Concurrent blocks in one XCD share <=2 B-panels (L2-resident, 16-way reuse);
    // A-panels are swept in lockstep across XCDs (L3-shared).
    const int raw = blockIdx.x;
    const int xq  = raw & 7;
    const int kq  = raw >> 3;                  // 0..47
    const int mTile = (kq & 15) * 256;
    const int nTile = (3 * xq + (kq >> 4)) * 256;

    // staging source (pre-inverse-swizzled global col): LDS row r halves swap when r&8
    const int sRow  = w * 16 + (lane >> 2);                       // 0..127
    const int sColE = ((lane & 3) * 8) ^ ((lane & 32) ? 16 : 0);  // elems in [0,32)
    const bf16* pa0 = A + (size_t)(mTile + sRow) * HIDDEN + sColE;
    const bf16* pa1 = pa0 + (size_t)128 * HIDDEN;
    int n0 = sRow, n1 = sRow + 128;
    if (nTile < QKW) { n0 = qk_perm(n0); n1 = qk_perm(n1); }
    const bf16* pb0 = Bt + (size_t)(nTile + n0) * HIDDEN + sColE;
    const bf16* pb1 = Bt + (size_t)(nTile + n1) * HIDDEN + sColE;

    const int colE = (quad * 8) ^ ((l15 & 8) ? 16 : 0);
    const bf16* lA0 = smem + (wm * 128 + l15) * 32 + colE;
    const bf16* lB0 = smem + 8192 + (wn * 64 + l15) * 32 + colE;

    f32x4 acc[8][4];
#pragma unroll
    for (int i = 0; i < 8; ++i)
#pragma unroll
        for (int j = 0; j < 4; ++j) acc[i][j] = (f32x4){0.f, 0.f, 0.f, 0.f};

    // prologue: stage K-tiles 0,1,2 (12 loads/wave in flight)
#pragma unroll
    for (int tt = 0; tt < 3; ++tt) {
        bf16* dA = smem + tt * 16384 + w * 512;
        async16(pa0 + tt * 32, dA);
        async16(pa1 + tt * 32, dA + 4096);
        async16(pb0 + tt * 32, dA + 8192);
        async16(pb1 + tt * 32, dA + 12288);
    }

    // main loop: 64 K-tiles; stage t+3 during t; one sync point per tile.
#pragma unroll 4
    for (int t = 0; t < 60; ++t) QKV_TILE(t, 1, 8);
    QKV_TILE(60, 1, 8);
    QKV_TILE(61, 0, 8);
    QKV_TILE(62, 0, 4);
    QKV_TILE(63, 0, 0);

    // ---- epilogue ----
    if (nTile < QKW) {
        // RoPE: frag nf holds cols d=(wn&1)*32+(nf&1)*16+l15 (+64 for nf+2), same lane.
        const int hbase = nTile + (wn >> 1) * 128 + (wn & 1) * 32;
#pragma unroll
        for (int mf = 0; mf < 8; ++mf)
#pragma unroll
            for (int r = 0; r < 4; ++r) {
                int row = mTile + wm * 128 + mf * 16 + quad * 4 + r;
                int s   = row & (SEQ - 1);
                float2 t0 = tab[s * 64 + (wn & 1) * 32 + l15];
                float2 t1 = tab[s * 64 + (wn & 1) * 32 + 16 + l15];
                size_t rb = (size_t)row * QKW + hbase + l15;
                float lo0 = acc[mf][0][r], hi0 = acc[mf][2][r];
                float lo1 = acc[mf][1][r], hi1 = acc[mf][3][r];
                qk[rb]      = (bf16)(lo0 * t0.x - hi0 * t0.y);
                qk[rb + 64] = (bf16)(hi0 * t0.x + lo0 * t0.y);
                qk[rb + 16] = (bf16)(lo1 * t1.x - hi1 * t1.y);
                qk[rb + 80] = (bf16)(hi1 * t1.x + lo1 * t1.y);
            }
    } else {
        // V region (identity n-map): store transposed, vt[feature][token]
#pragma unroll
        for (int mf = 0; mf < 8; ++mf)
#pragma unroll
            for (int nf = 0; nf < 4; ++nf) {
                int col_v = (nTile - QKW) + wn * 64 + nf * 16 + l15;
                int row0  = mTile + wm * 128 + mf * 16 + quad * 4;
                bf16x4 pk;
#pragma unroll
                for (int r = 0; r < 4; ++r) pk[r] = (bf16)acc[mf][nf][r];
                *(bf16x4*)(vtb + (size_t)col_v * BS + row0) = pk;
            }
    }
}

// ---------------------------------------------------------------- final proj: out = ao * Wo^T
// 128x256 tile, BK=32, 512 thr (8 waves 2M x 4N, wave tile 64x64), ring-4 x 24KB = 96KB LDS.
// Grid 256 = 32m x 8n -> EXACTLY one full round on 256 CUs (no tail quantization).
// Same barrier-minimal counted-vmcnt pipeline; 3 loads/tile/wave -> VMW(6) steady state.
#define OUT_TILE(T, DOSTAGE, VMN) do {                                          \
    VMW(VMN);                                                                   \
    BARX();                                                                     \
    const bf16* lAr = lA0 + ((T) & 3) * 12288;                                  \
    const bf16* lBr = lB0 + ((T) & 3) * 12288;                                  \
    bf16x8 bfr[4], af[4];                                                       \
    _Pragma("unroll") for (int nf = 0; nf < 4; ++nf)                            \
        bfr[nf] = *(const bf16x8*)(lBr + nf * 512);                             \
    _Pragma("unroll") for (int mf = 0; mf < 4; ++mf)                            \
        af[mf] = *(const bf16x8*)(lAr + mf * 512);                              \
    if (DOSTAGE) {                                                              \
        bf16* dS = smem + (((T) + 3) & 3) * 12288 + w * 512;                    \
        async16(pa0 + ((T) + 3) * 32, dS);                                      \
        async16(pb0 + ((T) + 3) * 32, dS + 4096);                               \
        async16(pb1 + ((T) + 3) * 32, dS + 8192);                               \
    }                                                                           \
    __builtin_amdgcn_s_setprio(1);                                              \
    _Pragma("unroll") for (int mf = 0; mf < 4; ++mf)                            \
    _Pragma("unroll") for (int nf = 0; nf < 4; ++nf)                            \
        acc[mf][nf] = __builtin_amdgcn_mfma_f32_16x16x32_bf16(                  \
            af[mf], bfr[nf], acc[mf][nf], 0, 0, 0);                             \
    __builtin_amdgcn_s_setprio(0);                                              \
} while (0)

__global__ __launch_bounds__(512, 2) void gemm_out(const bf16* __restrict__ A,
                                                   const bf16* __restrict__ Bt,
                                                   float* __restrict__ C) {
    __shared__ alignas(16) bf16 smem[49152];   // 96 KiB: 4 bufs x (A 4096 | B 8192)

    const int tid  = threadIdx.x;
    const int lane = tid & 63;
    const int w    = tid >> 6;
    const int l15  = lane & 15;
    const int quad = lane >> 4;
    const int wm   = w >> 2;       // 0..1
    const int wn   = w & 3;        // 0..3

    // XCD x owns nTile x; m-major sweep (B-panel 1MB L2-resident, 32-way reuse)
    const int raw = blockIdx.x;                // 0..255
    const int mTile = (raw >> 3) * 128;        // 32 m-tiles
    const int nTile = (raw & 7) * 256;         // 8 n-tiles

    const int sRow  = w * 16 + (lane >> 2);                       // 0..127
    const int sColE = ((lane & 3) * 8) ^ ((lane & 32) ? 16 : 0);
    const bf16* pa0 = A + (size_t)(mTile + sRow) * HIDDEN + sColE;
    const bf16* pb0 = Bt + (size_t)(nTile + sRow) * HIDDEN + sColE;
    const bf16* pb1 = pb0 + (size_t)128 * HIDDEN;

    const int colE = (quad * 8) ^ ((l15 & 8) ? 16 : 0);
    const bf16* lA0 = smem + (wm * 64 + l15) * 32 + colE;
    const bf16* lB0 = smem + 4096 + (wn * 64 + l15) * 32 + colE;

    f32x4 acc[4][4];
#pragma unroll
    for (int i = 0; i < 4; ++i)
#pragma unroll
        for (int j = 0; j < 4; ++j) acc[i][j] = (f32x4){0.f, 0.f, 0.f, 0.f};

    // prologue: stage K-tiles 0,1,2 (9 loads/wave in flight)
#pragma unroll
    for (int tt = 0; tt < 3; ++tt) {
        bf16* dS = smem + tt * 12288 + w * 512;
        async16(pa0 + tt * 32, dS);
        async16(pb0 + tt * 32, dS + 4096);
        async16(pb1 + tt * 32, dS + 8192);
    }

#pragma unroll 4
    for (int t = 0; t < 60; ++t) OUT_TILE(t, 1, 6);
    OUT_TILE(60, 1, 6);
    OUT_TILE(61, 0, 6);
    OUT_TILE(62, 0, 3);
    OUT_TILE(63, 0, 0);

#pragma unroll
    for (int mf = 0; mf < 4; ++mf)
#pragma unroll
        for (int nf = 0; nf < 4; ++nf)
#pragma unroll
            for (int r = 0; r < 4; ++r) {
                int row = mTile + wm * 64 + mf * 16 + quad * 4 + r;
                int col = nTile + wn * 64 + nf * 16 + l15;
                C[(size_t)row * HIDDEN + col] = acc[mf][nf][r];
            }
}

// ---------------------------------------------------------------- flash attention (S^T form)
__global__ __launch_bounds__(256) void attn_kernel(const bf16* __restrict__ qk,
                                                   const bf16* __restrict__ vt,
                                                   bf16* __restrict__ ao) {
    __shared__ bf16 Kls[64 * 128];   // [j][d], 16B chunk c of row j at c^(j&7)
    __shared__ bf16 Vls[128 * 64];   // [d][s], swizzled same

    const int tid  = threadIdx.x;
    const int lane = tid & 63;
    const int w    = tid >> 6;
    const int l15  = lane & 15;
    const int quad = lane >> 4;
    const int bid  = blockIdx.x;
    const int qt   = 31 - (bid >> 5);   // longest blocks dispatch first
    const int bh   = bid & 31;
    const int b    = bh >> 4;
    const int h    = bh & 15;
    const int qbase = qt * 64;
    const size_t seq0 = (size_t)b * SEQ;

    bf16x8 qf[4];
    {
        const bf16* qp = qk + (seq0 + qbase + w * 16 + l15) * QKW + h * HDIM + quad * 8;
#pragma unroll
        for (int ks = 0; ks < 4; ++ks) qf[ks] = *(const bf16x8*)(qp + ks * 32);
    }

    f32x4 o[8];
#pragma unroll
    for (int i = 0; i < 8; ++i) o[i] = (f32x4){0.f, 0.f, 0.f, 0.f};
    float m_s = -3e38f, l_s = 0.f;
    const int qg = qbase + w * 16 + l15;

    const int krow = lane >> 4;
    const int kp   = lane & 15;
    const int vrow = lane >> 3;
    const int vp   = lane & 7;
    const int sw   = l15 & 7;

    for (int t = 0; t <= qt; ++t) {
        const int kb = t * 64;
#pragma unroll
        for (int i = 0; i < 4; ++i) {
            int j = w * 16 + i * 4 + krow;
            int c = (kp & 8) | ((kp & 7) ^ (j & 7));
            async16(qk + (seq0 + kb + j) * QKW + HIDDEN + h * HDIM + c * 8,
                    Kls + (w * 4 + i) * 512);
        }
#pragma unroll
        for (int i = 0; i < 4; ++i) {
            int d = w * 32 + i * 8 + vrow;
            int c = vp ^ (d & 7);
            async16(vt + (size_t)(h * HDIM + d) * (size_t)BS + seq0 + kb + c * 8,
                    Vls + (w * 4 + i) * 512);
        }
        __syncthreads();

        f32x4 sa[4];
#pragma unroll
        for (int ni = 0; ni < 4; ++ni) sa[ni] = (f32x4){0.f, 0.f, 0.f, 0.f};
#pragma unroll
        for (int ni = 0; ni < 4; ++ni)
#pragma unroll
            for (int ks = 0; ks < 4; ++ks) {
                bf16x8 kf = *(const bf16x8*)(Kls + (ni * 16 + l15) * 128 +
                                             (((ks * 4 + quad) ^ sw) << 3));
                sa[ni] = __builtin_amdgcn_mfma_f32_16x16x32_bf16(kf, qf[ks], sa[ni], 0, 0, 0);
            }

        const float scale = 0.08838834764831845f * 1.4426950408889634f;
        float rmax = -3e38f;
        const bool diag = (t == qt);
#pragma unroll
        for (int ni = 0; ni < 4; ++ni)
#pragma unroll
            for (int r = 0; r < 4; ++r) {
                float sv = sa[ni][r] * scale;
                if (diag) {
                    int jg = kb + ni * 16 + quad * 4 + r;
                    if (jg > qg) sv = -1e30f;
                }
                sa[ni][r] = sv;
                rmax = fmaxf(rmax, sv);
            }
        rmax = fmaxf(rmax, __shfl_xor(rmax, 16));
        rmax = fmaxf(rmax, __shfl_xor(rmax, 32));

        float mn = fmaxf(m_s, rmax);
        float alpha = exp2f(m_s - mn);
        m_s = mn;
        float rsum = 0.f;
        b4u pb[4];
#pragma unroll
        for (int ni = 0; ni < 4; ++ni)
#pragma unroll
            for (int r = 0; r < 4; ++r) {
                float e = exp2f(sa[ni][r] - mn);
                rsum += e;
                pb[ni].h[r] = (bf16)e;
            }
        rsum += __shfl_xor(rsum, 16);
        rsum += __shfl_xor(rsum, 32);
        l_s = l_s * alpha + rsum;

        if (__ballot(alpha != 1.f) != 0ull) {
#pragma unroll
            for (int n2 = 0; n2 < 8; ++n2)
#pragma unroll
                for (int r = 0; r < 4; ++r) o[n2][r] *= alpha;
        }

#pragma unroll
        for (int n2 = 0; n2 < 8; ++n2)
#pragma unroll
            for (int ni = 0; ni < 4; ++ni) {
                b4u vf;
                vf.h = *(const bf16x4*)(Vls + (n2 * 16 + l15) * 64 +
                                        ((((ni * 2 + (quad >> 1)) ^ sw) << 3) + (quad & 1) * 4));
                o[n2] = __builtin_amdgcn_mfma_f32_16x16x16bf16_1k(vf.s, pb[ni].s, o[n2], 0, 0, 0);
            }
        __syncthreads();
    }

    const float inv = 1.0f / l_s;
    bf16* op = ao + (seq0 + qg) * HIDDEN + h * HDIM + quad * 4;
#pragma unroll
    for (int n2 = 0; n2 < 8; ++n2) {
        bf16x4 pk;
#pragma unroll
        for (int r = 0; r < 4; ++r) pk[r] = (bf16)(o[n2][r] * inv);
        *(bf16x4*)(op + n2 * 16) = pk;
    }
}

// ---------------------------------------------------------------- launch
extern "C" void kernel_launch(void* const* d_in, const int* in_sizes, int n_in,
                              void* d_out, int out_size, void* d_ws, size_t ws_size,
                              hipStream_t stream) {
    const float* hs = (const float*)d_in[0];
    const float* Wq = (const float*)d_in[1];
    const float* Wk = (const float*)d_in[2];
    const float* Wv = (const float*)d_in[3];
    const float* Wo = (const float*)d_in[4];
    const int* pos  = (const int*)d_in[6];
    float* out = (float*)d_out;

    bf16* hs_b = (bf16*)d_ws;                               //  8,388,608 el
    bf16* wqkv = hs_b + (size_t)8388608;                    // 12,582,912 el [6144][2048]
    bf16* wo_b = wqkv + (size_t)12582912;                   //  4,194,304 el
    bf16* qkb  = wo_b + (size_t)4194304;                    // 16,777,216 el [4096][4096]
    bf16* vtb  = qkb + (size_t)16777216;                    //  8,388,608 el [2048][4096]
    bf16* ao   = vtb + (size_t)8388608;                     //  8,388,608 el
    float2* tab = (float2*)ao;  // 1 MB, consumed by gemm_qkv BEFORE attn writes ao

    cast_all<<<25088, 256, 0, stream>>>(hs, Wq, Wk, Wv, Wo, pos, hs_b, wqkv, wo_b, tab);
    gemm_qkv<<<384, 512, 0, stream>>>(hs_b, wqkv, tab, qkb, vtb);
    attn_kernel<<<1024, 256, 0, stream>>>(qkb, vtb, ao);
    gemm_out<<<256, 512, 0, stream>>>(ao, wo_b, out);
}

// Round 3
// 361.826 us; speedup vs baseline: 1.1288x; 1.0273x over previous
//
#include <hip/hip_runtime.h>
#include <cstdint>
#include <cstddef>

typedef __bf16 bf16;
typedef __bf16 bf16x4 __attribute__((ext_vector_type(4)));
typedef __bf16 bf16x8 __attribute__((ext_vector_type(8)));
typedef float  f32x4  __attribute__((ext_vector_type(4)));
typedef short  s16x4  __attribute__((ext_vector_type(4)));

#define HIDDEN 2048
#define NHEADS 16
#define HDIM   128
#define BSZ    2
#define SEQ    2048
#define BS     (BSZ*SEQ)     /* 4096 rows */
#define QKW    (2*HIDDEN)    /* 4096: Q|K concat width */

union b4u { bf16x4 h; s16x4 s; };

// async global->LDS, 16B per lane. LDS dest = wave-uniform base + lane*16.
__device__ __forceinline__ void async16(const bf16* g, bf16* l) {
    __builtin_amdgcn_global_load_lds(
        (const __attribute__((address_space(1))) unsigned int*)g,
        (__attribute__((address_space(3))) unsigned int*)l, 16, 0, 0);
}

#define BARX()  asm volatile("s_barrier" ::: "memory")
#define VMW(N)  asm volatile("s_waitcnt vmcnt(" #N ")" ::: "memory")

// ---------------------------------------------------------------- fused casts + rope table
__global__ __launch_bounds__(256) void cast_all(const float* __restrict__ hs,
                                                const float* __restrict__ Wq,
                                                const float* __restrict__ Wk,
                                                const float* __restrict__ Wv,
                                                const float* __restrict__ Wo,
                                                const int* __restrict__ pos,
                                                bf16* __restrict__ hs_b,
                                                bf16* __restrict__ wqkv,
                                                bf16* __restrict__ wo_b,
                                                float2* __restrict__ tab) {
    int i = blockIdx.x * 256 + threadIdx.x;
    if (i >= 6291456) {                       // rope table region
        int j = i - 6291456;                  // 0..131071
        int s = j >> 6, p = j & 63;
        float t = (float)pos[s];
        float inv = expf(-(float)(2 * p) * (9.2103403719761836f / 128.0f));
        float sn, cs;
        sincosf(t * inv, &sn, &cs);
        tab[j] = make_float2(cs, sn);
        return;
    }
    const float* src; bf16* dst; int off;
    if (i < 2097152) { src = hs; dst = hs_b; off = i; }
    else {
        int j = i - 2097152;
        int r = j >> 20;
        off = j & 1048575;
        if      (r == 0) { src = Wq; dst = wqkv; }
        else if (r == 1) { src = Wk; dst = wqkv + (size_t)4194304; }
        else if (r == 2) { src = Wv; dst = wqkv + (size_t)8388608; }
        else             { src = Wo; dst = wo_b; }
    }
    const float4 v = ((const float4*)src)[off];
    bf16x4 o;
    o.x = (bf16)v.x; o.y = (bf16)v.y; o.z = (bf16)v.z; o.w = (bf16)v.w;
    ((bf16x4*)dst)[off] = o;
}

// ---------------------------------------------------------------- Q|K GEMM + RoPE
// 256x256 tile, BK=32, 512 thr (8 waves 2M x 4N), ring-4 LDS, counted vmcnt,
// st_16x32 swizzle, setprio. Grid 256 = EXACTLY one full round on 256 CUs.
__device__ __forceinline__ int qk_perm(int n) {
    int wl = n >> 6, j = n & 63;
    return ((wl >> 1) << 7) | ((j >> 5) << 6) | ((wl & 1) << 5) | (j & 31);
}

#define QKV_TILE(T, DOSTAGE, VMN) do {                                          \
    VMW(VMN);                                                                   \
    BARX();                                                                     \
    const bf16* lAr = lA0 + ((T) & 3) * 16384;                                  \
    const bf16* lBr = lB0 + ((T) & 3) * 16384;                                  \
    bf16x8 bfr[4], af[4];                                                       \
    _Pragma("unroll") for (int nf = 0; nf < 4; ++nf)                            \
        bfr[nf] = *(const bf16x8*)(lBr + nf * 512);                             \
    _Pragma("unroll") for (int mf = 0; mf < 4; ++mf)                            \
        af[mf] = *(const bf16x8*)(lAr + mf * 512);                              \
    if (DOSTAGE) {                                                              \
        bf16* dA = smem + (((T) + 3) & 3) * 16384 + w * 512;                    \
        async16(pa0 + ((T) + 3) * 32, dA);                                      \
        async16(pa1 + ((T) + 3) * 32, dA + 4096);                               \
    }                                                                           \
    __builtin_amdgcn_s_setprio(1);                                              \
    _Pragma("unroll") for (int mf = 0; mf < 4; ++mf)                            \
    _Pragma("unroll") for (int nf = 0; nf < 4; ++nf)                            \
        acc[mf][nf] = __builtin_amdgcn_mfma_f32_16x16x32_bf16(                  \
            af[mf], bfr[nf], acc[mf][nf], 0, 0, 0);                             \
    __builtin_amdgcn_s_setprio(0);                                              \
    _Pragma("unroll") for (int mf = 0; mf < 4; ++mf)                            \
        af[mf] = *(const bf16x8*)(lAr + 2048 + mf * 512);                       \
    if (DOSTAGE) {                                                              \
        bf16* dB = smem + (((T) + 3) & 3) * 16384 + 8192 + w * 512;             \
        async16(pb0 + ((T) + 3) * 32, dB);                                      \
        async16(pb1 + ((T) + 3) * 32, dB + 4096);                               \
    }                                                                           \
    __builtin_amdgcn_s_setprio(1);                                              \
    _Pragma("unroll") for (int mf = 0; mf < 4; ++mf)                            \
    _Pragma("unroll") for (int nf = 0; nf < 4; ++nf)                            \
        acc[4 + mf][nf] = __builtin_amdgcn_mfma_f32_16x16x32_bf16(              \
            af[mf], bfr[nf], acc[4 + mf][nf], 0, 0, 0);                         \
    __builtin_amdgcn_s_setprio(0);                                              \
} while (0)

__global__ __launch_bounds__(512, 2) void gemm_qk(const bf16* __restrict__ A,
                                                  const bf16* __restrict__ Bt,
                                                  const float2* __restrict__ tab,
                                                  bf16* __restrict__ qk) {
    __shared__ alignas(16) bf16 smem[65536];   // 128 KiB: 4 bufs x (A 8192 | B 8192)

    const int tid  = threadIdx.x;
    const int lane = tid & 63;
    const int w    = tid >> 6;
    const int l15  = lane & 15;
    const int quad = lane >> 4;
    const int wm   = w >> 2;       // 0..1
    const int wn   = w & 3;        // 0..3

    // raw&7 = XCD under round-robin dispatch -> XCD x owns n-tiles {2x,2x+1} (B L2-res),
    // m-major sweep shares A across XCDs through L3.
    const int raw = blockIdx.x;                // 0..255
    const int kq  = raw >> 3;                  // 0..31
    const int mTile = (kq & 15) * 256;
    const int nTile = (2 * (raw & 7) + (kq >> 4)) * 256;

    const int sRow  = w * 16 + (lane >> 2);                       // 0..127
    const int sColE = ((lane & 3) * 8) ^ ((lane & 32) ? 16 : 0);  // elems in [0,32)
    const bf16* pa0 = A + (size_t)(mTile + sRow) * HIDDEN + sColE;
    const bf16* pa1 = pa0 + (size_t)128 * HIDDEN;
    const int n0 = qk_perm(sRow), n1 = qk_perm(sRow + 128);
    const bf16* pb0 = Bt + (size_t)(nTile + n0) * HIDDEN + sColE;
    const bf16* pb1 = Bt + (size_t)(nTile + n1) * HIDDEN + sColE;

    const int colE = (quad * 8) ^ ((l15 & 8) ? 16 : 0);
    const bf16* lA0 = smem + (wm * 128 + l15) * 32 + colE;
    const bf16* lB0 = smem + 8192 + (wn * 64 + l15) * 32 + colE;

    f32x4 acc[8][4];
#pragma unroll
    for (int i = 0; i < 8; ++i)
#pragma unroll
        for (int j = 0; j < 4; ++j) acc[i][j] = (f32x4){0.f, 0.f, 0.f, 0.f};

#pragma unroll
    for (int tt = 0; tt < 3; ++tt) {
        bf16* dA = smem + tt * 16384 + w * 512;
        async16(pa0 + tt * 32, dA);
        async16(pa1 + tt * 32, dA + 4096);
        async16(pb0 + tt * 32, dA + 8192);
        async16(pb1 + tt * 32, dA + 12288);
    }

#pragma unroll 4
    for (int t = 0; t < 60; ++t) QKV_TILE(t, 1, 8);
    QKV_TILE(60, 1, 8);
    QKV_TILE(61, 0, 8);
    QKV_TILE(62, 0, 4);
    QKV_TILE(63, 0, 0);

    // RoPE epilogue: frag nf holds cols d=(wn&1)*32+(nf&1)*16+l15 (+64 for nf+2), same lane.
    const int hbase = nTile + (wn >> 1) * 128 + (wn & 1) * 32;
#pragma unroll
    for (int mf = 0; mf < 8; ++mf)
#pragma unroll
        for (int r = 0; r < 4; ++r) {
            int row = mTile + wm * 128 + mf * 16 + quad * 4 + r;
            int s   = row & (SEQ - 1);
            float2 t0 = tab[s * 64 + (wn & 1) * 32 + l15];
            float2 t1 = tab[s * 64 + (wn & 1) * 32 + 16 + l15];
            size_t rb = (size_t)row * QKW + hbase + l15;
            float lo0 = acc[mf][0][r], hi0 = acc[mf][2][r];
            float lo1 = acc[mf][1][r], hi1 = acc[mf][3][r];
            qk[rb]      = (bf16)(lo0 * t0.x - hi0 * t0.y);
            qk[rb + 64] = (bf16)(hi0 * t0.x + lo0 * t0.y);
            qk[rb + 16] = (bf16)(lo1 * t1.x - hi1 * t1.y);
            qk[rb + 80] = (bf16)(hi1 * t1.x + lo1 * t1.y);
        }
}

// ---------------------------------------------------------------- 128x256 pipeline tile
// (shared by gemm_v and gemm_out): BK=32, 8 waves 2M x 4N, wave tile 64x64,
// ring-4 x 24KB = 96KB LDS, 3 loads/tile/wave -> VMW(6) steady state.
#define OUT_TILE(T, DOSTAGE, VMN) do {                                          \
    VMW(VMN);                                                                   \
    BARX();                                                                     \
    const bf16* lAr = lA0 + ((T) & 3) * 12288;                                  \
    const bf16* lBr = lB0 + ((T) & 3) * 12288;                                  \
    bf16x8 bfr[4], af[4];                                                       \
    _Pragma("unroll") for (int nf = 0; nf < 4; ++nf)                            \
        bfr[nf] = *(const bf16x8*)(lBr + nf * 512);                             \
    _Pragma("unroll") for (int mf = 0; mf < 4; ++mf)                            \
        af[mf] = *(const bf16x8*)(lAr + mf * 512);                              \
    if (DOSTAGE) {                                                              \
        bf16* dS = smem + (((T) + 3) & 3) * 12288 + w * 512;                    \
        async16(pa0 + ((T) + 3) * 32, dS);                                      \
        async16(pb0 + ((T) + 3) * 32, dS + 4096);                               \
        async16(pb1 + ((T) + 3) * 32, dS + 8192);                               \
    }                                                                           \
    __builtin_amdgcn_s_setprio(1);                                              \
    _Pragma("unroll") for (int mf = 0; mf < 4; ++mf)                            \
    _Pragma("unroll") for (int nf = 0; nf < 4; ++nf)                            \
        acc[mf][nf] = __builtin_amdgcn_mfma_f32_16x16x32_bf16(                  \
            af[mf], bfr[nf], acc[mf][nf], 0, 0, 0);                             \
    __builtin_amdgcn_s_setprio(0);                                              \
} while (0)

#define OUT_PROLOGUE()                                                          \
    const int tid  = threadIdx.x;                                               \
    const int lane = tid & 63;                                                  \
    const int w    = tid >> 6;                                                  \
    const int l15  = lane & 15;                                                 \
    const int quad = lane >> 4;                                                 \
    const int wm   = w >> 2;                                                    \
    const int wn   = w & 3;                                                     \
    const int raw = blockIdx.x;                                                 \
    const int mTile = (raw >> 3) * 128;                                         \
    const int nTile = (raw & 7) * 256;                                          \
    const int sRow  = w * 16 + (lane >> 2);                                     \
    const int sColE = ((lane & 3) * 8) ^ ((lane & 32) ? 16 : 0);                \
    const bf16* pa0 = A + (size_t)(mTile + sRow) * HIDDEN + sColE;              \
    const bf16* pb0 = Bt + (size_t)(nTile + sRow) * HIDDEN + sColE;             \
    const bf16* pb1 = pb0 + (size_t)128 * HIDDEN;                               \
    const int colE = (quad * 8) ^ ((l15 & 8) ? 16 : 0);                         \
    const bf16* lA0 = smem + (wm * 64 + l15) * 32 + colE;                       \
    const bf16* lB0 = smem + 4096 + (wn * 64 + l15) * 32 + colE;                \
    f32x4 acc[4][4];                                                            \
    _Pragma("unroll") for (int i = 0; i < 4; ++i)                               \
    _Pragma("unroll") for (int j = 0; j < 4; ++j)                               \
        acc[i][j] = (f32x4){0.f, 0.f, 0.f, 0.f};                                \
    _Pragma("unroll") for (int tt = 0; tt < 3; ++tt) {                          \
        bf16* dS = smem + tt * 12288 + w * 512;                                 \
        async16(pa0 + tt * 32, dS);                                             \
        async16(pb0 + tt * 32, dS + 4096);                                      \
        async16(pb1 + tt * 32, dS + 8192);                                      \
    }                                                                           \
    _Pragma("unroll 4") for (int t = 0; t < 60; ++t) OUT_TILE(t, 1, 6);         \
    OUT_TILE(60, 1, 6);                                                         \
    OUT_TILE(61, 0, 6);                                                         \
    OUT_TILE(62, 0, 3);                                                         \
    OUT_TILE(63, 0, 0);

// V projection: A[4096 tok][2048] x Wv^T -> vt[feature][token] (transposed bf16 store)
__global__ __launch_bounds__(512, 2) void gemm_v(const bf16* __restrict__ A,
                                                 const bf16* __restrict__ Bt,
                                                 bf16* __restrict__ vtb) {
    __shared__ alignas(16) bf16 smem[49152];   // 96 KiB
    OUT_PROLOGUE()
#pragma unroll
    for (int mf = 0; mf < 4; ++mf)
#pragma unroll
        for (int nf = 0; nf < 4; ++nf) {
            int col_v = nTile + wn * 64 + nf * 16 + l15;        // feature
            int row0  = mTile + wm * 64 + mf * 16 + quad * 4;   // token
            bf16x4 pk;
#pragma unroll
            for (int r = 0; r < 4; ++r) pk[r] = (bf16)acc[mf][nf][r];
            *(bf16x4*)(vtb + (size_t)col_v * BS + row0) = pk;
        }
}

// final proj: out = ao * Wo^T (fp32 row-major store)
__global__ __launch_bounds__(512, 2) void gemm_out(const bf16* __restrict__ A,
                                                   const bf16* __restrict__ Bt,
                                                   float* __restrict__ C) {
    __shared__ alignas(16) bf16 smem[49152];   // 96 KiB
    OUT_PROLOGUE()
#pragma unroll
    for (int mf = 0; mf < 4; ++mf)
#pragma unroll
        for (int nf = 0; nf < 4; ++nf)
#pragma unroll
            for (int r = 0; r < 4; ++r) {
                int row = mTile + wm * 64 + mf * 16 + quad * 4 + r;
                int col = nTile + wn * 64 + nf * 16 + l15;
                C[(size_t)row * HIDDEN + col] = acc[mf][nf][r];
            }
}

// ---------------------------------------------------------------- flash attention (S^T form)
// Double-buffered K/V in LDS (2 x 32KB), counted vmcnt: stage t+1 issued BEFORE the
// wait for t; two raw s_barriers per tile, never a vmcnt(0) drain until the last tile.
__global__ __launch_bounds__(256) void attn_kernel(const bf16* __restrict__ qk,
                                                   const bf16* __restrict__ vt,
                                                   bf16* __restrict__ ao) {
    __shared__ bf16 Kls[2][64 * 128];   // [j][d], 16B chunk c of row j at c^(j&7)
    __shared__ bf16 Vls[2][128 * 64];   // [d][s], swizzled same

    const int tid  = threadIdx.x;
    const int lane = tid & 63;
    const int w    = tid >> 6;
    const int l15  = lane & 15;
    const int quad = lane >> 4;
    const int bid  = blockIdx.x;
    const int qt   = 31 - (bid >> 5);   // longest blocks dispatch first
    const int bh   = bid & 31;
    const int b    = bh >> 4;
    const int h    = bh & 15;
    const int qbase = qt * 64;
    const size_t seq0 = (size_t)b * SEQ;

    bf16x8 qf[4];
    {
        const bf16* qp = qk + (seq0 + qbase + w * 16 + l15) * QKW + h * HDIM + quad * 8;
#pragma unroll
        for (int ks = 0; ks < 4; ++ks) qf[ks] = *(const bf16x8*)(qp + ks * 32);
    }
    // pin the Q-fragment vmcnt wait HERE (preheader), so the compiler doesn't
    // re-emit a drain inside the pipelined loop.
#pragma unroll
    for (int ks = 0; ks < 4; ++ks)
        asm volatile("" :: "v"(*(const f32x4*)&qf[ks]));

    f32x4 o[8];
#pragma unroll
    for (int i = 0; i < 8; ++i) o[i] = (f32x4){0.f, 0.f, 0.f, 0.f};
    float m_s = -3e38f, l_s = 0.f;
    const int qg = qbase + w * 16 + l15;

    const int krow = lane >> 4;
    const int kp   = lane & 15;
    const int vrow = lane >> 3;
    const int vp   = lane & 7;
    const int sw   = l15 & 7;

    // stage K/V tile t into buffer buf
#define ATTN_STAGE(T, BUF) do {                                                  \
        const int kb_ = (T) * 64;                                                \
        _Pragma("unroll") for (int i = 0; i < 4; ++i) {                          \
            int j = w * 16 + i * 4 + krow;                                       \
            int c = (kp & 8) | ((kp & 7) ^ (j & 7));                             \
            async16(qk + (seq0 + kb_ + j) * QKW + HIDDEN + h * HDIM + c * 8,     \
                    &Kls[BUF][(w * 4 + i) * 512]);                               \
        }                                                                        \
        _Pragma("unroll") for (int i = 0; i < 4; ++i) {                          \
            int d = w * 32 + i * 8 + vrow;                                       \
            int c = vp ^ (d & 7);                                                \
            async16(vt + (size_t)(h * HDIM + d) * (size_t)BS + seq0 + kb_ + c * 8,\
                    &Vls[BUF][(w * 4 + i) * 512]);                               \
        }                                                                        \
    } while (0)

    ATTN_STAGE(0, 0);

    for (int t = 0; t <= qt; ++t) {
        if (t < qt) { ATTN_STAGE(t + 1, (t + 1) & 1); VMW(8); }
        else        { VMW(0); }
        BARX();
        const bf16* Kb = Kls[t & 1];
        const bf16* Vb = Vls[t & 1];
        const int kb = t * 64;

        f32x4 sa[4];
#pragma unroll
        for (int ni = 0; ni < 4; ++ni) sa[ni] = (f32x4){0.f, 0.f, 0.f, 0.f};
#pragma unroll
        for (int ni = 0; ni < 4; ++ni)
#pragma unroll
            for (int ks = 0; ks < 4; ++ks) {
                bf16x8 kf = *(const bf16x8*)(Kb + (ni * 16 + l15) * 128 +
                                             (((ks * 4 + quad) ^ sw) << 3));
                sa[ni] = __builtin_amdgcn_mfma_f32_16x16x32_bf16(kf, qf[ks], sa[ni], 0, 0, 0);
            }

        const float scale = 0.08838834764831845f * 1.4426950408889634f;
        float rmax = -3e38f;
        const bool diag = (t == qt);
#pragma unroll
        for (int ni = 0; ni < 4; ++ni)
#pragma unroll
            for (int r = 0; r < 4; ++r) {
                float sv = sa[ni][r] * scale;
                if (diag) {
                    int jg = kb + ni * 16 + quad * 4 + r;
                    if (jg > qg) sv = -1e30f;
                }
                sa[ni][r] = sv;
                rmax = fmaxf(rmax, sv);
            }
        rmax = fmaxf(rmax, __shfl_xor(rmax, 16));
        rmax = fmaxf(rmax, __shfl_xor(rmax, 32));

        float mn = fmaxf(m_s, rmax);
        float alpha = exp2f(m_s - mn);
        m_s = mn;
        float rsum = 0.f;
        b4u pb[4];
#pragma unroll
        for (int ni = 0; ni < 4; ++ni)
#pragma unroll
            for (int r = 0; r < 4; ++r) {
                float e = exp2f(sa[ni][r] - mn);
                rsum += e;
                pb[ni].h[r] = (bf16)e;
            }
        rsum += __shfl_xor(rsum, 16);
        rsum += __shfl_xor(rsum, 32);
        l_s = l_s * alpha + rsum;

        if (__ballot(alpha != 1.f) != 0ull) {
#pragma unroll
            for (int n2 = 0; n2 < 8; ++n2)
#pragma unroll
                for (int r = 0; r < 4; ++r) o[n2][r] *= alpha;
        }

#pragma unroll
        for (int n2 = 0; n2 < 8; ++n2)
#pragma unroll
            for (int ni = 0; ni < 4; ++ni) {
                b4u vf;
                vf.h = *(const bf16x4*)(Vb + (n2 * 16 + l15) * 64 +
                                        ((((ni * 2 + (quad >> 1)) ^ sw) << 3) + (quad & 1) * 4));
                o[n2] = __builtin_amdgcn_mfma_f32_16x16x16bf16_1k(vf.s, pb[ni].s, o[n2], 0, 0, 0);
            }
        BARX();   // reads of this buffer done -> next iter may re-stage it
    }
#undef ATTN_STAGE

    const float inv = 1.0f / l_s;
    bf16* op = ao + (seq0 + qg) * HIDDEN + h * HDIM + quad * 4;
#pragma unroll
    for (int n2 = 0; n2 < 8; ++n2) {
        bf16x4 pk;
#pragma unroll
        for (int r = 0; r < 4; ++r) pk[r] = (bf16)(o[n2][r] * inv);
        *(bf16x4*)(op + n2 * 16) = pk;
    }
}

// ---------------------------------------------------------------- launch
extern "C" void kernel_launch(void* const* d_in, const int* in_sizes, int n_in,
                              void* d_out, int out_size, void* d_ws, size_t ws_size,
                              hipStream_t stream) {
    const float* hs = (const float*)d_in[0];
    const float* Wq = (const float*)d_in[1];
    const float* Wk = (const float*)d_in[2];
    const float* Wv = (const float*)d_in[3];
    const float* Wo = (const float*)d_in[4];
    const int* pos  = (const int*)d_in[6];
    float* out = (float*)d_out;

    bf16* hs_b = (bf16*)d_ws;                               //  8,388,608 el
    bf16* wqkv = hs_b + (size_t)8388608;                    // 12,582,912 el [6144][2048]
    bf16* wo_b = wqkv + (size_t)12582912;                   //  4,194,304 el
    bf16* qkb  = wo_b + (size_t)4194304;                    // 16,777,216 el [4096][4096]
    bf16* vtb  = qkb + (size_t)16777216;                    //  8,388,608 el [2048][4096]
    bf16* ao   = vtb + (size_t)8388608;                     //  8,388,608 el
    float2* tab = (float2*)ao;  // 1 MB, consumed by gemm_qk BEFORE attn writes ao

    cast_all<<<25088, 256, 0, stream>>>(hs, Wq, Wk, Wv, Wo, pos, hs_b, wqkv, wo_b, tab);
    gemm_qk<<<256, 512, 0, stream>>>(hs_b, wqkv, tab, qkb);
    gemm_v<<<256, 512, 0, stream>>>(hs_b, wqkv + (size_t)8388608, vtb);
    attn_kernel<<<1024, 256, 0, stream>>>(qkb, vtb, ao);
    gemm_out<<<256, 512, 0, stream>>>(ao, wo_b, out);
}

// Round 4
// 359.354 us; speedup vs baseline: 1.1366x; 1.0069x over previous
//
#include <hip/hip_runtime.h>
#include <cstdint>
#include <cstddef>

typedef __bf16 bf16;
typedef __bf16 bf16x4 __attribute__((ext_vector_type(4)));
typedef __bf16 bf16x8 __attribute__((ext_vector_type(8)));
typedef float  f32x4  __attribute__((ext_vector_type(4)));
typedef short  s16x4  __attribute__((ext_vector_type(4)));

#define HIDDEN 2048
#define NHEADS 16
#define HDIM   128
#define BSZ    2
#define SEQ    2048
#define BS     (BSZ*SEQ)     /* 4096 rows */
#define QKW    (2*HIDDEN)    /* 4096: Q|K concat width */

union b4u { bf16x4 h; s16x4 s; };

// async global->LDS, 16B per lane. LDS dest = wave-uniform base + lane*16.
__device__ __forceinline__ void async16(const bf16* g, bf16* l) {
    __builtin_amdgcn_global_load_lds(
        (const __attribute__((address_space(1))) unsigned int*)g,
        (__attribute__((address_space(3))) unsigned int*)l, 16, 0, 0);
}

#define BARX()  asm volatile("s_barrier" ::: "memory")
#define VMW(N)  asm volatile("s_waitcnt vmcnt(" #N ")" ::: "memory")

// raw v_exp_f32: exp2 is the native op, skip OCML fixups (args are <= 8, large-neg -> 0)
__device__ __forceinline__ float ex2(float x) {
    float r; asm("v_exp_f32 %0, %1" : "=v"(r) : "v"(x)); return r;
}

// ---------------------------------------------------------------- fused casts + rope table
__global__ __launch_bounds__(256) void cast_all(const float* __restrict__ hs,
                                                const float* __restrict__ Wq,
                                                const float* __restrict__ Wk,
                                                const float* __restrict__ Wv,
                                                const float* __restrict__ Wo,
                                                const int* __restrict__ pos,
                                                bf16* __restrict__ hs_b,
                                                bf16* __restrict__ wqkv,
                                                bf16* __restrict__ wo_b,
                                                float2* __restrict__ tab) {
    int i = blockIdx.x * 256 + threadIdx.x;
    if (i >= 6291456) {                       // rope table region
        int j = i - 6291456;                  // 0..131071
        int s = j >> 6, p = j & 63;
        float t = (float)pos[s];
        float inv = expf(-(float)(2 * p) * (9.2103403719761836f / 128.0f));
        float sn, cs;
        sincosf(t * inv, &sn, &cs);
        tab[j] = make_float2(cs, sn);
        return;
    }
    const float* src; bf16* dst; int off;
    if (i < 2097152) { src = hs; dst = hs_b; off = i; }
    else {
        int j = i - 2097152;
        int r = j >> 20;
        off = j & 1048575;
        if      (r == 0) { src = Wq; dst = wqkv; }
        else if (r == 1) { src = Wk; dst = wqkv + (size_t)4194304; }
        else if (r == 2) { src = Wv; dst = wqkv + (size_t)8388608; }
        else             { src = Wo; dst = wo_b; }
    }
    const float4 v = ((const float4*)src)[off];
    bf16x4 o;
    o.x = (bf16)v.x; o.y = (bf16)v.y; o.z = (bf16)v.z; o.w = (bf16)v.w;
    ((bf16x4*)dst)[off] = o;
}

// ---------------------------------------------------------------- Q|K GEMM + RoPE
// 256x256 tile, BK=32, 512 thr (8 waves 2M x 4N), ring-4 LDS, counted vmcnt,
// st_16x32 swizzle, setprio. Grid 256 = EXACTLY one full round on 256 CUs.
// Q region written PRE-SCALED by 1/sqrt(128)*log2(e) so attn's S is exp2-domain.
__device__ __forceinline__ int qk_perm(int n) {
    int wl = n >> 6, j = n & 63;
    return ((wl >> 1) << 7) | ((j >> 5) << 6) | ((wl & 1) << 5) | (j & 31);
}

#define QKV_TILE(T, DOSTAGE, VMN) do {                                          \
    VMW(VMN);                                                                   \
    BARX();                                                                     \
    const bf16* lAr = lA0 + ((T) & 3) * 16384;                                  \
    const bf16* lBr = lB0 + ((T) & 3) * 16384;                                  \
    bf16x8 bfr[4], af[4];                                                       \
    _Pragma("unroll") for (int nf = 0; nf < 4; ++nf)                            \
        bfr[nf] = *(const bf16x8*)(lBr + nf * 512);                             \
    _Pragma("unroll") for (int mf = 0; mf < 4; ++mf)                            \
        af[mf] = *(const bf16x8*)(lAr + mf * 512);                              \
    if (DOSTAGE) {                                                              \
        bf16* dA = smem + (((T) + 3) & 3) * 16384 + w * 512;                    \
        async16(pa0 + ((T) + 3) * 32, dA);                                      \
        async16(pa1 + ((T) + 3) * 32, dA + 4096);                               \
    }                                                                           \
    __builtin_amdgcn_s_setprio(1);                                              \
    _Pragma("unroll") for (int mf = 0; mf < 4; ++mf)                            \
    _Pragma("unroll") for (int nf = 0; nf < 4; ++nf)                            \
        acc[mf][nf] = __builtin_amdgcn_mfma_f32_16x16x32_bf16(                  \
            af[mf], bfr[nf], acc[mf][nf], 0, 0, 0);                             \
    __builtin_amdgcn_s_setprio(0);                                              \
    _Pragma("unroll") for (int mf = 0; mf < 4; ++mf)                            \
        af[mf] = *(const bf16x8*)(lAr + 2048 + mf * 512);                       \
    if (DOSTAGE) {                                                              \
        bf16* dB = smem + (((T) + 3) & 3) * 16384 + 8192 + w * 512;             \
        async16(pb0 + ((T) + 3) * 32, dB);                                      \
        async16(pb1 + ((T) + 3) * 32, dB + 4096);                               \
    }                                                                           \
    __builtin_amdgcn_s_setprio(1);                                              \
    _Pragma("unroll") for (int mf = 0; mf < 4; ++mf)                            \
    _Pragma("unroll") for (int nf = 0; nf < 4; ++nf)                            \
        acc[4 + mf][nf] = __builtin_amdgcn_mfma_f32_16x16x32_bf16(              \
            af[mf], bfr[nf], acc[4 + mf][nf], 0, 0, 0);                         \
    __builtin_amdgcn_s_setprio(0);                                              \
} while (0)

__global__ __launch_bounds__(512, 2) void gemm_qk(const bf16* __restrict__ A,
                                                  const bf16* __restrict__ Bt,
                                                  const float2* __restrict__ tab,
                                                  bf16* __restrict__ qk) {
    __shared__ alignas(16) bf16 smem[65536];   // 128 KiB: 4 bufs x (A 8192 | B 8192)

    const int tid  = threadIdx.x;
    const int lane = tid & 63;
    const int w    = tid >> 6;
    const int l15  = lane & 15;
    const int quad = lane >> 4;
    const int wm   = w >> 2;       // 0..1
    const int wn   = w & 3;        // 0..3

    const int raw = blockIdx.x;                // 0..255
    const int kq  = raw >> 3;                  // 0..31
    const int mTile = (kq & 15) * 256;
    const int nTile = (2 * (raw & 7) + (kq >> 4)) * 256;

    const int sRow  = w * 16 + (lane >> 2);                       // 0..127
    const int sColE = ((lane & 3) * 8) ^ ((lane & 32) ? 16 : 0);  // elems in [0,32)
    const bf16* pa0 = A + (size_t)(mTile + sRow) * HIDDEN + sColE;
    const bf16* pa1 = pa0 + (size_t)128 * HIDDEN;
    const int n0 = qk_perm(sRow), n1 = qk_perm(sRow + 128);
    const bf16* pb0 = Bt + (size_t)(nTile + n0) * HIDDEN + sColE;
    const bf16* pb1 = Bt + (size_t)(nTile + n1) * HIDDEN + sColE;

    const int colE = (quad * 8) ^ ((l15 & 8) ? 16 : 0);
    const bf16* lA0 = smem + (wm * 128 + l15) * 32 + colE;
    const bf16* lB0 = smem + 8192 + (wn * 64 + l15) * 32 + colE;

    f32x4 acc[8][4];
#pragma unroll
    for (int i = 0; i < 8; ++i)
#pragma unroll
        for (int j = 0; j < 4; ++j) acc[i][j] = (f32x4){0.f, 0.f, 0.f, 0.f};

#pragma unroll
    for (int tt = 0; tt < 3; ++tt) {
        bf16* dA = smem + tt * 16384 + w * 512;
        async16(pa0 + tt * 32, dA);
        async16(pa1 + tt * 32, dA + 4096);
        async16(pb0 + tt * 32, dA + 8192);
        async16(pb1 + tt * 32, dA + 12288);
    }

#pragma unroll 4
    for (int t = 0; t < 60; ++t) QKV_TILE(t, 1, 8);
    QKV_TILE(60, 1, 8);
    QKV_TILE(61, 0, 8);
    QKV_TILE(62, 0, 4);
    QKV_TILE(63, 0, 0);

    // RoPE epilogue; Q region (cols < 2048) gets the softmax scale folded in.
    const float qs = (nTile < HIDDEN) ? (0.08838834764831845f * 1.4426950408889634f) : 1.0f;
    const int hbase = nTile + (wn >> 1) * 128 + (wn & 1) * 32;
#pragma unroll
    for (int mf = 0; mf < 8; ++mf)
#pragma unroll
        for (int r = 0; r < 4; ++r) {
            int row = mTile + wm * 128 + mf * 16 + quad * 4 + r;
            int s   = row & (SEQ - 1);
            float2 t0 = tab[s * 64 + (wn & 1) * 32 + l15];
            float2 t1 = tab[s * 64 + (wn & 1) * 32 + 16 + l15];
            size_t rb = (size_t)row * QKW + hbase + l15;
            float lo0 = acc[mf][0][r], hi0 = acc[mf][2][r];
            float lo1 = acc[mf][1][r], hi1 = acc[mf][3][r];
            qk[rb]      = (bf16)((lo0 * t0.x - hi0 * t0.y) * qs);
            qk[rb + 64] = (bf16)((hi0 * t0.x + lo0 * t0.y) * qs);
            qk[rb + 16] = (bf16)((lo1 * t1.x - hi1 * t1.y) * qs);
            qk[rb + 80] = (bf16)((hi1 * t1.x + lo1 * t1.y) * qs);
        }
}

// ---------------------------------------------------------------- 128x256 pipeline tile
#define OUT_TILE(T, DOSTAGE, VMN) do {                                          \
    VMW(VMN);                                                                   \
    BARX();                                                                     \
    const bf16* lAr = lA0 + ((T) & 3) * 12288;                                  \
    const bf16* lBr = lB0 + ((T) & 3) * 12288;                                  \
    bf16x8 bfr[4], af[4];                                                       \
    _Pragma("unroll") for (int nf = 0; nf < 4; ++nf)                            \
        bfr[nf] = *(const bf16x8*)(lBr + nf * 512);                             \
    _Pragma("unroll") for (int mf = 0; mf < 4; ++mf)                            \
        af[mf] = *(const bf16x8*)(lAr + mf * 512);                              \
    if (DOSTAGE) {                                                              \
        bf16* dS = smem + (((T) + 3) & 3) * 12288 + w * 512;                    \
        async16(pa0 + ((T) + 3) * 32, dS);                                      \
        async16(pb0 + ((T) + 3) * 32, dS + 4096);                               \
        async16(pb1 + ((T) + 3) * 32, dS + 8192);                               \
    }                                                                           \
    __builtin_amdgcn_s_setprio(1);                                              \
    _Pragma("unroll") for (int mf = 0; mf < 4; ++mf)                            \
    _Pragma("unroll") for (int nf = 0; nf < 4; ++nf)                            \
        acc[mf][nf] = __builtin_amdgcn_mfma_f32_16x16x32_bf16(                  \
            af[mf], bfr[nf], acc[mf][nf], 0, 0, 0);                             \
    __builtin_amdgcn_s_setprio(0);                                              \
} while (0)

#define OUT_PROLOGUE()                                                          \
    const int tid  = threadIdx.x;                                               \
    const int lane = tid & 63;                                                  \
    const int w    = tid >> 6;                                                  \
    const int l15  = lane & 15;                                                 \
    const int quad = lane >> 4;                                                 \
    const int wm   = w >> 2;                                                    \
    const int wn   = w & 3;                                                     \
    const int raw = blockIdx.x;                                                 \
    const int mTile = (raw >> 3) * 128;                                         \
    const int nTile = (raw & 7) * 256;                                          \
    const int sRow  = w * 16 + (lane >> 2);                                     \
    const int sColE = ((lane & 3) * 8) ^ ((lane & 32) ? 16 : 0);                \
    const bf16* pa0 = A + (size_t)(mTile + sRow) * HIDDEN + sColE;              \
    const bf16* pb0 = Bt + (size_t)(nTile + sRow) * HIDDEN + sColE;             \
    const bf16* pb1 = pb0 + (size_t)128 * HIDDEN;                               \
    const int colE = (quad * 8) ^ ((l15 & 8) ? 16 : 0);                         \
    const bf16* lA0 = smem + (wm * 64 + l15) * 32 + colE;                       \
    const bf16* lB0 = smem + 4096 + (wn * 64 + l15) * 32 + colE;                \
    f32x4 acc[4][4];                                                            \
    _Pragma("unroll") for (int i = 0; i < 4; ++i)                               \
    _Pragma("unroll") for (int j = 0; j < 4; ++j)                               \
        acc[i][j] = (f32x4){0.f, 0.f, 0.f, 0.f};                                \
    _Pragma("unroll") for (int tt = 0; tt < 3; ++tt) {                          \
        bf16* dS = smem + tt * 12288 + w * 512;                                 \
        async16(pa0 + tt * 32, dS);                                             \
        async16(pb0 + tt * 32, dS + 4096);                                      \
        async16(pb1 + tt * 32, dS + 8192);                                      \
    }                                                                           \
    _Pragma("unroll 4") for (int t = 0; t < 60; ++t) OUT_TILE(t, 1, 6);         \
    OUT_TILE(60, 1, 6);                                                         \
    OUT_TILE(61, 0, 6);                                                         \
    OUT_TILE(62, 0, 3);                                                         \
    OUT_TILE(63, 0, 0);

// V projection: A[4096 tok][2048] x Wv^T -> vt[feature][token] (transposed bf16 store)
__global__ __launch_bounds__(512, 2) void gemm_v(const bf16* __restrict__ A,
                                                 const bf16* __restrict__ Bt,
                                                 bf16* __restrict__ vtb) {
    __shared__ alignas(16) bf16 smem[49152];   // 96 KiB
    OUT_PROLOGUE()
#pragma unroll
    for (int mf = 0; mf < 4; ++mf)
#pragma unroll
        for (int nf = 0; nf < 4; ++nf) {
            int col_v = nTile + wn * 64 + nf * 16 + l15;        // feature
            int row0  = mTile + wm * 64 + mf * 16 + quad * 4;   // token
            bf16x4 pk;
#pragma unroll
            for (int r = 0; r < 4; ++r) pk[r] = (bf16)acc[mf][nf][r];
            *(bf16x4*)(vtb + (size_t)col_v * BS + row0) = pk;
        }
}

// final proj: out = ao * Wo^T (fp32 row-major store)
__global__ __launch_bounds__(512, 2) void gemm_out(const bf16* __restrict__ A,
                                                   const bf16* __restrict__ Bt,
                                                   float* __restrict__ C) {
    __shared__ alignas(16) bf16 smem[49152];   // 96 KiB
    OUT_PROLOGUE()
#pragma unroll
    for (int mf = 0; mf < 4; ++mf)
#pragma unroll
        for (int nf = 0; nf < 4; ++nf)
#pragma unroll
            for (int r = 0; r < 4; ++r) {
                int row = mTile + wm * 64 + mf * 16 + quad * 4 + r;
                int col = nTile + wn * 64 + nf * 16 + l15;
                C[(size_t)row * HIDDEN + col] = acc[mf][nf][r];
            }
}

// ---------------------------------------------------------------- flash attention (S^T form)
// 8 waves x QBLK=128, 512 blocks ALL co-resident (2 blocks/CU, 64KB LDS each), paired so
// each CU's two blocks sum to a constant 34 tiles. Q pre-scaled (exp2 domain). Dbuf K/V
// with counted vmcnt; hoisted LDS read bases (all variation in ds_read immediates);
// raw v_exp_f32; defer-max (T13): skip o-rescale unless tile max grew > 8.
__global__ __launch_bounds__(512, 4) void attn_kernel(const bf16* __restrict__ qk,
                                                      const bf16* __restrict__ vt,
                                                      bf16* __restrict__ ao) {
    __shared__ bf16 Kls[2][64 * 128];   // [j][d], 16B chunk c of row j at c^(j&7)
    __shared__ bf16 Vls[2][128 * 64];   // [d][s], swizzled same

    const int tid  = threadIdx.x;
    const int lane = tid & 63;
    const int w    = tid >> 6;          // 0..7
    const int l15  = lane & 15;
    const int quad = lane >> 4;
    const int bid  = blockIdx.x;
    // balanced pairing: first 256 bids qb2 = 15-(idx>>5), next 256 qb2 = idx>>5.
    // CU c gets bids {c, c+256} (round-robin heuristic) -> per-CU tiles = 34 const.
    const int half = bid >> 8;
    const int idx  = bid & 255;
    const int qb2  = half ? (idx >> 5) : 15 - (idx >> 5);
    const int bh   = idx & 31;
    const int b    = bh >> 4;
    const int h    = bh & 15;
    const int qbase = qb2 * 128;
    const int nt    = 2 * qb2 + 2;      // always even
    const size_t seq0 = (size_t)b * SEQ;

    // Q fragments (pre-scaled by gemm_qk)
    bf16x8 qf[4];
    {
        const bf16* qp = qk + (seq0 + qbase + w * 16 + l15) * QKW + h * HDIM + quad * 8;
#pragma unroll
        for (int ks = 0; ks < 4; ++ks) qf[ks] = *(const bf16x8*)(qp + ks * 32);
    }
#pragma unroll
    for (int ks = 0; ks < 4; ++ks)
        asm volatile("" :: "v"(*(const f32x4*)&qf[ks]));   // pin Q wait to preheader

    f32x4 o[8];
#pragma unroll
    for (int i = 0; i < 8; ++i) o[i] = (f32x4){0.f, 0.f, 0.f, 0.f};
    float m_s = -3e38f, l_s = 0.f;
    const int qg = qbase + w * 16 + l15;

    const int krow = lane >> 4;
    const int kp   = lane & 15;
    const int vrow = lane >> 3;
    const int vp   = lane & 7;
    const int sw   = l15 & 7;

    // ---- staging sources: uniform SGPR base + 32-bit lane offsets ----
    const bf16* qksrc = qk + seq0 * QKW + HIDDEN + h * HDIM;          // uniform
    const bf16* vtsrc = vt + (size_t)h * HDIM * BS + seq0;            // uniform
    int koff[2], voff[2];
#pragma unroll
    for (int i = 0; i < 2; ++i) {
        int c = w * 2 + i;
        int j = c * 4 + krow;
        int c2 = (kp & 8) | ((kp & 7) ^ (j & 7));
        koff[i] = j * QKW + c2 * 8;
        int d = c * 8 + vrow;
        int cv = vp ^ (d & 7);
        voff[i] = d * BS + cv * 8;
    }

    // ---- hoisted LDS read bases (buffer 0); BUF/ni/n2 variation -> ds offsets ----
    const bf16* kbase[4];
#pragma unroll
    for (int ks = 0; ks < 4; ++ks)
        kbase[ks] = &Kls[0][l15 * 128 + (((ks * 4 + quad) ^ sw) << 3)];
    const bf16* vbase[4];
#pragma unroll
    for (int ni = 0; ni < 4; ++ni)
        vbase[ni] = &Vls[0][l15 * 64 + ((((ni * 2 + (quad >> 1)) ^ sw) << 3) + (quad & 1) * 4)];

#define ATTN_STAGE(T, BUF) do {                                                  \
        const int kb_ = (T) * 64;                                                \
        _Pragma("unroll") for (int i = 0; i < 2; ++i)                            \
            async16(qksrc + (size_t)kb_ * QKW + koff[i],                         \
                    &Kls[BUF][(w * 2 + i) * 512]);                               \
        _Pragma("unroll") for (int i = 0; i < 2; ++i)                            \
            async16(vtsrc + kb_ + voff[i],                                       \
                    &Vls[BUF][(w * 2 + i) * 512]);                               \
    } while (0)

#define ATTN_TILE(T, BUF) do {                                                   \
        if ((T) + 1 < nt) { ATTN_STAGE((T) + 1, (BUF) ^ 1); VMW(4); }            \
        else              { VMW(0); }                                            \
        BARX();                                                                  \
        const int kb = (T) * 64;                                                 \
        f32x4 sa[4];                                                             \
        _Pragma("unroll") for (int ni = 0; ni < 4; ++ni)                         \
            sa[ni] = (f32x4){0.f, 0.f, 0.f, 0.f};                                \
        _Pragma("unroll") for (int ni = 0; ni < 4; ++ni)                         \
        _Pragma("unroll") for (int ks = 0; ks < 4; ++ks) {                       \
            bf16x8 kf = *(const bf16x8*)(kbase[ks] + (BUF) * 8192 + ni * 2048);  \
            sa[ni] = __builtin_amdgcn_mfma_f32_16x16x32_bf16(kf, qf[ks], sa[ni], 0, 0, 0); \
        }                                                                        \
        float rmax = -3e38f;                                                     \
        const bool diag = ((T) >= nt - 2);                                       \
        _Pragma("unroll") for (int ni = 0; ni < 4; ++ni)                         \
        _Pragma("unroll") for (int r = 0; r < 4; ++r) {                          \
            float sv = sa[ni][r];                                                \
            if (diag && (kb + ni * 16 + quad * 4 + r > qg)) sv = -1e30f;         \
            sa[ni][r] = sv;                                                      \
            rmax = fmaxf(rmax, sv);                                              \
        }                                                                        \
        rmax = fmaxf(rmax, __shfl_xor(rmax, 16));                                \
        rmax = fmaxf(rmax, __shfl_xor(rmax, 32));                                \
        if (__ballot(rmax > m_s + 8.f) != 0ull) {                                \
            float mn = fmaxf(m_s, rmax);                                         \
            float al = ex2(m_s - mn);                                            \
            m_s = mn; l_s *= al;                                                 \
            _Pragma("unroll") for (int n2 = 0; n2 < 8; ++n2)                     \
            _Pragma("unroll") for (int r = 0; r < 4; ++r) o[n2][r] *= al;        \
        }                                                                        \
        float rsum = 0.f;                                                        \
        b4u pb[4];                                                               \
        _Pragma("unroll") for (int ni = 0; ni < 4; ++ni)                         \
        _Pragma("unroll") for (int r = 0; r < 4; ++r) {                          \
            float e = ex2(sa[ni][r] - m_s);                                      \
            rsum += e;                                                           \
            pb[ni].h[r] = (bf16)e;                                               \
        }                                                                        \
        rsum += __shfl_xor(rsum, 16);                                            \
        rsum += __shfl_xor(rsum, 32);                                            \
        l_s += rsum;                                                             \
        _Pragma("unroll") for (int n2 = 0; n2 < 8; ++n2)                         \
        _Pragma("unroll") for (int ni = 0; ni < 4; ++ni) {                       \
            b4u vf;                                                              \
            vf.h = *(const bf16x4*)(vbase[ni] + (BUF) * 8192 + n2 * 1024);       \
            o[n2] = __builtin_amdgcn_mfma_f32_16x16x16bf16_1k(vf.s, pb[ni].s, o[n2], 0, 0, 0); \
        }                                                                        \
        BARX();                                                                  \
    } while (0)

    ATTN_STAGE(0, 0);
    for (int t = 0; t < nt; t += 2) {
        ATTN_TILE(t, 0);
        ATTN_TILE(t + 1, 1);
    }
#undef ATTN_TILE
#undef ATTN_STAGE

    const float inv = 1.0f / l_s;
    bf16* op = ao + (seq0 + qg) * HIDDEN + h * HDIM + quad * 4;
#pragma unroll
    for (int n2 = 0; n2 < 8; ++n2) {
        bf16x4 pk;
#pragma unroll
        for (int r = 0; r < 4; ++r) pk[r] = (bf16)(o[n2][r] * inv);
        *(bf16x4*)(op + n2 * 16) = pk;
    }
}

// ---------------------------------------------------------------- launch
extern "C" void kernel_launch(void* const* d_in, const int* in_sizes, int n_in,
                              void* d_out, int out_size, void* d_ws, size_t ws_size,
                              hipStream_t stream) {
    const float* hs = (const float*)d_in[0];
    const float* Wq = (const float*)d_in[1];
    const float* Wk = (const float*)d_in[2];
    const float* Wv = (const float*)d_in[3];
    const float* Wo = (const float*)d_in[4];
    const int* pos  = (const int*)d_in[6];
    float* out = (float*)d_out;

    bf16* hs_b = (bf16*)d_ws;                               //  8,388,608 el
    bf16* wqkv = hs_b + (size_t)8388608;                    // 12,582,912 el [6144][2048]
    bf16* wo_b = wqkv + (size_t)12582912;                   //  4,194,304 el
    bf16* qkb  = wo_b + (size_t)4194304;                    // 16,777,216 el [4096][4096]
    bf16* vtb  = qkb + (size_t)16777216;                    //  8,388,608 el [2048][4096]
    bf16* ao   = vtb + (size_t)8388608;                     //  8,388,608 el
    float2* tab = (float2*)ao;  // 1 MB, consumed by gemm_qk BEFORE attn writes ao

    cast_all<<<25088, 256, 0, stream>>>(hs, Wq, Wk, Wv, Wo, pos, hs_b, wqkv, wo_b, tab);
    gemm_qk<<<256, 512, 0, stream>>>(hs_b, wqkv, tab, qkb);
    gemm_v<<<256, 512, 0, stream>>>(hs_b, wqkv + (size_t)8388608, vtb);
    attn_kernel<<<512, 512, 0, stream>>>(qkb, vtb, ao);
    gemm_out<<<256, 512, 0, stream>>>(ao, wo_b, out);
}